// Round 1
// baseline (870.987 us; speedup 1.0000x reference)
//
#include <hip/hip_runtime.h>

// ---------------------------------------------------------------------------
// OctreeResBlock on MI355X (gfx950), round 0: bf16 MFMA baseline.
//   h  = x^T                              [N,256]  (bf16)
//   c1 = relu(bn(h @ W1a^T))              [N,128]
//   c2 = relu(bn(octree_conv(c1)))        [N,128]
//   c3 = bn(c2 @ W1b^T)                   [N,512]
//   sc = bn(h @ Wc^T)                     [N,512]
//   out = relu(c3 + sc)^T                 [512,N] fp32
// BN is training-mode batch stats (biased var), eps=1e-5.
// ---------------------------------------------------------------------------

typedef __bf16 bf16x8 __attribute__((ext_vector_type(8)));
typedef float f32x4 __attribute__((ext_vector_type(4)));
typedef unsigned short u16x8 __attribute__((ext_vector_type(8)));

__device__ __forceinline__ unsigned short f2bfu(float f) {
  union { float f; unsigned u; } v; v.f = f;
  unsigned r = v.u + 0x7fffu + ((v.u >> 16) & 1u);   // round-to-nearest-even
  return (unsigned short)(r >> 16);
}
__device__ __forceinline__ float bfu2f(unsigned short s) {
  union { unsigned u; float f; } v; v.u = ((unsigned)s) << 16;
  return v.f;
}

// --- weights prep: fp32 -> bf16; W3 [k][c][d] -> w3t [k][d][c] --------------
__global__ __launch_bounds__(256) void prep_weights(
    const float* __restrict__ W1a, const float* __restrict__ W3,
    const float* __restrict__ W1b, const float* __restrict__ Wc,
    unsigned short* __restrict__ w1a, unsigned short* __restrict__ w3t,
    unsigned short* __restrict__ w1b, unsigned short* __restrict__ wc) {
  int i = blockIdx.x * 256 + threadIdx.x;
  int stride = gridDim.x * 256;
  for (; i < 442368; i += stride) {
    if (i < 32768)  w1a[i] = f2bfu(W1a[i]);
    if (i < 65536)  w1b[i] = f2bfu(W1b[i]);
    if (i < 131072) wc[i]  = f2bfu(Wc[i]);
    int k = i >> 14, rr = i & 16383;
    int d = rr >> 7, c = rr & 127;
    w3t[i] = f2bfu(W3[(k << 14) + (c << 7) + d]);
  }
}

// --- x [256][M] fp32 -> h [M][256] bf16 (LDS tile transpose) ----------------
__global__ __launch_bounds__(256) void transpose_x(
    const float* __restrict__ x, unsigned short* __restrict__ h, int M) {
  __shared__ float tile[64][65];
  int n0 = blockIdx.x * 64, c0 = blockIdx.y * 64;
  int t = threadIdx.x;
  int nl = t & 63;
#pragma unroll
  for (int i = 0; i < 16; ++i) {
    int cl = i * 4 + (t >> 6);
    int n = n0 + nl;
    tile[cl][nl] = (n < M) ? x[(size_t)(c0 + cl) * M + n] : 0.f;
  }
  __syncthreads();
  int cl = t & 63;
#pragma unroll
  for (int i = 0; i < 16; ++i) {
    int nl2 = i * 4 + (t >> 6);
    int n = n0 + nl2;
    if (n < M) h[(size_t)n * 256 + c0 + cl] = f2bfu(tile[cl][nl2]);
  }
}

// --- generic GEMM: C[M][Nc] = A[M][Kd] * W[Nc][Kd]^T, all bf16 --------------
// 64x64 tile, 4 waves, each wave 16 rows x 64 cols via 4x mfma_16x16x32.
__global__ __launch_bounds__(256) void gemm_bt(
    const unsigned short* __restrict__ A, const unsigned short* __restrict__ W,
    unsigned short* __restrict__ C, int M, int Kd, int Nc) {
  __shared__ unsigned short sA[64 * 40];  // stride 40 elems (80B) to dodge bank conflicts
  __shared__ unsigned short sB[64 * 40];
  int t = threadIdx.x, wave = t >> 6, lane = t & 63;
  int m0 = blockIdx.x * 64, n0 = blockIdx.y * 64;
  f32x4 acc[4] = {};
  int r = t >> 2, ch = (t & 3) * 8;
  int arow = m0 + r;
  bool aval = arow < M;
  const unsigned short* Ar = A + (size_t)arow * Kd + ch;
  const unsigned short* Wr = W + (size_t)(n0 + r) * Kd + ch;
  int aoff = (wave * 16 + (lane & 15)) * 40 + (lane >> 4) * 8;
  int boffb = (lane & 15) * 40 + (lane >> 4) * 8;
  for (int k0 = 0; k0 < Kd; k0 += 32) {
    u16x8 av = {0, 0, 0, 0, 0, 0, 0, 0};
    if (aval) av = *(const u16x8*)(Ar + k0);
    u16x8 bv = *(const u16x8*)(Wr + k0);
    *(u16x8*)(sA + r * 40 + ch) = av;
    *(u16x8*)(sB + r * 40 + ch) = bv;
    __syncthreads();
    bf16x8 a = __builtin_bit_cast(bf16x8, *(const u16x8*)(sA + aoff));
#pragma unroll
    for (int nb = 0; nb < 4; ++nb) {
      bf16x8 b = __builtin_bit_cast(bf16x8, *(const u16x8*)(sB + boffb + nb * 16 * 40));
      acc[nb] = __builtin_amdgcn_mfma_f32_16x16x32_bf16(a, b, acc[nb], 0, 0, 0);
    }
    __syncthreads();
  }
  int rb = wave * 16 + (lane >> 4) * 4;
  int col = lane & 15;
#pragma unroll
  for (int nb = 0; nb < 4; ++nb)
#pragma unroll
    for (int i = 0; i < 4; ++i) {
      int n = m0 + rb + i;
      if (n < M) C[(size_t)n * Nc + n0 + nb * 16 + col] = f2bfu(acc[nb][i]);
    }
}

// --- octree conv: c2p[n][d] = sum_k sum_c c1[neigh[n][k]][c] * w3t[k][d][c] -
// 64x128 tile, 4 waves, each wave 16 rows x 128 cols (8 accs).
__global__ __launch_bounds__(256) void octree_gemm(
    const unsigned short* __restrict__ c1, const int* __restrict__ neigh,
    const unsigned short* __restrict__ w3t, unsigned short* __restrict__ c2p, int M) {
  __shared__ unsigned short sA[64 * 40];
  __shared__ unsigned short sB[128 * 40];
  __shared__ int nidx[64 * 27];
  int t = threadIdx.x, wave = t >> 6, lane = t & 63;
  int m0 = blockIdx.x * 64;
  for (int i = t; i < 64 * 27; i += 256) {
    int row = i / 27;
    nidx[i] = (m0 + row < M) ? neigh[(size_t)m0 * 27 + i] : M;  // M == empty
  }
  __syncthreads();
  f32x4 acc[8] = {};
  int r = t >> 2, ch = (t & 3) * 8;
  int aoff = (wave * 16 + (lane & 15)) * 40 + (lane >> 4) * 8;
  int boffb = (lane & 15) * 40 + (lane >> 4) * 8;
  int jb = t >> 2, chb = (t & 3) * 8;
  for (int k = 0; k < 27; ++k) {
    int mrow = nidx[r * 27 + k];
    const unsigned short* arp = c1 + (size_t)mrow * 128 + ch;
    const unsigned short* wk = w3t + (size_t)k * 16384;
#pragma unroll
    for (int ccq = 0; ccq < 4; ++ccq) {
      int cc = ccq * 32;
      u16x8 av = {0, 0, 0, 0, 0, 0, 0, 0};
      if (mrow < M) av = *(const u16x8*)(arp + cc);
      *(u16x8*)(sA + r * 40 + ch) = av;
      *(u16x8*)(sB + jb * 40 + chb) = *(const u16x8*)(wk + (size_t)jb * 128 + cc + chb);
      *(u16x8*)(sB + (jb + 64) * 40 + chb) = *(const u16x8*)(wk + (size_t)(jb + 64) * 128 + cc + chb);
      __syncthreads();
      bf16x8 a = __builtin_bit_cast(bf16x8, *(const u16x8*)(sA + aoff));
#pragma unroll
      for (int nb = 0; nb < 8; ++nb) {
        bf16x8 b = __builtin_bit_cast(bf16x8, *(const u16x8*)(sB + boffb + nb * 16 * 40));
        acc[nb] = __builtin_amdgcn_mfma_f32_16x16x32_bf16(a, b, acc[nb], 0, 0, 0);
      }
      __syncthreads();
    }
  }
  int rb = wave * 16 + (lane >> 4) * 4;
  int col = lane & 15;
#pragma unroll
  for (int nb = 0; nb < 8; ++nb)
#pragma unroll
    for (int i = 0; i < 4; ++i) {
      int n = m0 + rb + i;
      if (n < M) c2p[(size_t)n * 128 + nb * 16 + col] = f2bfu(acc[nb][i]);
    }
}

// --- per-channel sum / sumsq partials (deterministic, no atomics) -----------
__global__ __launch_bounds__(256) void colstats(
    const unsigned short* __restrict__ P, int M, int C, int rowsPerBlock,
    float* __restrict__ partials) {
  int t = threadIdx.x, b = blockIdx.x;
  int r0 = b * rowsPerBlock;
  int r1 = r0 + rowsPerBlock; if (r1 > M) r1 = M;
  if (C >= 256) {
    for (int c = t; c < C; c += 256) {
      float s = 0.f, s2 = 0.f;
      for (int rr = r0; rr < r1; ++rr) {
        float v = bfu2f(P[(size_t)rr * C + c]);
        s += v; s2 += v * v;
      }
      partials[(size_t)b * 2 * C + c] = s;
      partials[(size_t)b * 2 * C + C + c] = s2;
    }
  } else {  // C == 128
    int sub = t >> 7;
    int c = t & 127;
    float s = 0.f, s2 = 0.f;
    for (int rr = r0 + sub; rr < r1; rr += 2) {
      float v = bfu2f(P[(size_t)rr * C + c]);
      s += v; s2 += v * v;
    }
    __shared__ float sh[256], sh2[256];
    sh[t] = s; sh2[t] = s2;
    __syncthreads();
    if (sub == 0) {
      s += sh[t + 128]; s2 += sh2[t + 128];
      partials[(size_t)b * 2 * C + c] = s;
      partials[(size_t)b * 2 * C + C + c] = s2;
    }
  }
}

// --- reduce partials -> scale/shift: ss[c]=g*rsqrt(var+eps), ss[C+c]=b-mu*scale
__global__ void bn_finalize(const float* __restrict__ partials, int nb, int C, int M,
                            const float* __restrict__ g, const float* __restrict__ bt,
                            float* __restrict__ ss) {
  int c = blockIdx.x * blockDim.x + threadIdx.x;
  if (c >= C) return;
  float s = 0.f, s2 = 0.f;
  for (int b = 0; b < nb; ++b) {
    s += partials[(size_t)b * 2 * C + c];
    s2 += partials[(size_t)b * 2 * C + C + c];
  }
  float mean = s / (float)M;
  float var = s2 / (float)M - mean * mean;
  float sc = g[c] * rsqrtf(var + 1e-5f);
  ss[c] = sc;
  ss[C + c] = bt[c] - mean * sc;
}

// --- elementwise BN + ReLU, bf16 in/out -------------------------------------
__global__ __launch_bounds__(256) void bnrelu(
    const unsigned short* __restrict__ P, const float* __restrict__ ss,
    unsigned short* __restrict__ Aout, int total, int Cmask) {
  int i = (blockIdx.x * 256 + threadIdx.x) * 8;
  if (i >= total) return;
  u16x8 v = *(const u16x8*)(P + i);
  int c0 = i & Cmask;
  int C = Cmask + 1;
  u16x8 o;
#pragma unroll
  for (int j = 0; j < 8; ++j) {
    float f = bfu2f(v[j]) * ss[c0 + j] + ss[C + c0 + j];
    o[j] = f2bfu(fmaxf(f, 0.f));
  }
  *(u16x8*)(Aout + i) = o;
}

// --- final: out[c][n] = relu(bn3(c3p) + bnsc(scp)), transposed fp32 write ---
__global__ __launch_bounds__(256) void final_out(
    const unsigned short* __restrict__ c3p, const unsigned short* __restrict__ scp,
    const float* __restrict__ ss3, const float* __restrict__ sssc,
    float* __restrict__ out, int M) {
  __shared__ float tile[64][65];
  int n0 = blockIdx.x * 64, c0 = blockIdx.y * 64;
  int t = threadIdx.x;
  int cl = t & 63;
#pragma unroll
  for (int i = 0; i < 16; ++i) {
    int nl = i * 4 + (t >> 6);
    int n = n0 + nl;
    float v = 0.f;
    if (n < M) {
      int c = c0 + cl;
      float a = bfu2f(c3p[(size_t)n * 512 + c]) * ss3[c] + ss3[512 + c];
      float b = bfu2f(scp[(size_t)n * 512 + c]) * sssc[c] + sssc[512 + c];
      v = fmaxf(a + b, 0.f);
    }
    tile[nl][cl] = v;
  }
  __syncthreads();
  int nl = t & 63;
#pragma unroll
  for (int i = 0; i < 16; ++i) {
    int cl2 = i * 4 + (t >> 6);
    int n = n0 + nl;
    if (n < M) out[(size_t)(c0 + cl2) * M + n0 + nl] = tile[nl][cl2];
  }
}

extern "C" void kernel_launch(void* const* d_in, const int* in_sizes, int n_in,
                              void* d_out, int out_size, void* d_ws, size_t ws_size,
                              hipStream_t stream) {
  const float* x   = (const float*)d_in[0];
  const int* neigh = (const int*)d_in[1];
  const float* W1a = (const float*)d_in[2];
  const float* g1a = (const float*)d_in[3];
  const float* b1a = (const float*)d_in[4];
  const float* W3  = (const float*)d_in[5];
  const float* g3  = (const float*)d_in[6];
  const float* b3  = (const float*)d_in[7];
  const float* W1b = (const float*)d_in[8];
  const float* g1b = (const float*)d_in[9];
  const float* b1b = (const float*)d_in[10];
  const float* Wc  = (const float*)d_in[11];
  const float* gc  = (const float*)d_in[12];
  const float* bc  = (const float*)d_in[13];
  float* out = (float*)d_out;

  const int M = in_sizes[1] / 27;          // 60000 nodes
  const int MT = (M + 63) / 64;            // 938 row tiles

  char* ws = (char*)d_ws;
  unsigned short* h   = (unsigned short*)(ws + 0);           // [M][256] bf16
  unsigned short* wA  = (unsigned short*)(ws + 30720000);    // activations c1/c2 [M][128]
  unsigned short* wP  = (unsigned short*)(ws + 46080000);    // pre-activations [M][128]
  unsigned short* c3p = (unsigned short*)(ws + 61440000);    // [M][512]
  unsigned short* scp = (unsigned short*)(ws + 122880000);   // [M][512]
  unsigned short* w1a = (unsigned short*)(ws + 184320000);   // [128][256]
  unsigned short* w3t = (unsigned short*)(ws + 184385536);   // [27][128][128] d-major
  unsigned short* w1b = (unsigned short*)(ws + 185270272);   // [512][128]
  unsigned short* wc  = (unsigned short*)(ws + 185401344);   // [512][256]
  float* partials     = (float*)(ws + 185663488);            // 240 * 2 * 512 fp32
  float* ss1  = (float*)(ws + 186646528);
  float* ss2  = (float*)(ws + 186647552);
  float* ss3  = (float*)(ws + 186648576);
  float* sssc = (float*)(ws + 186652672);

  const int rpb = (M + 239) / 240;
  const int bnGrid = (M * 128 / 8 + 255) / 256;

  prep_weights<<<1728, 256, 0, stream>>>(W1a, W3, W1b, Wc, w1a, w3t, w1b, wc);
  transpose_x<<<dim3(MT, 4), 256, 0, stream>>>(x, h, M);

  // c1 = relu(bn(h @ W1a^T))
  gemm_bt<<<dim3(MT, 2), 256, 0, stream>>>(h, w1a, wP, M, 256, 128);
  colstats<<<240, 256, 0, stream>>>(wP, M, 128, rpb, partials);
  bn_finalize<<<1, 256, 0, stream>>>(partials, 240, 128, M, g1a, b1a, ss1);
  bnrelu<<<bnGrid, 256, 0, stream>>>(wP, ss1, wA, M * 128, 127);

  // c2 = relu(bn(octree_conv(c1)))
  octree_gemm<<<MT, 256, 0, stream>>>(wA, neigh, w3t, wP, M);
  colstats<<<240, 256, 0, stream>>>(wP, M, 128, rpb, partials);
  bn_finalize<<<1, 256, 0, stream>>>(partials, 240, 128, M, g3, b3, ss2);
  bnrelu<<<bnGrid, 256, 0, stream>>>(wP, ss2, wA, M * 128, 127);

  // c3_pre = c2 @ W1b^T ; sc_pre = h @ Wc^T
  gemm_bt<<<dim3(MT, 8), 256, 0, stream>>>(wA, w1b, c3p, M, 128, 512);
  gemm_bt<<<dim3(MT, 8), 256, 0, stream>>>(h, wc, scp, M, 256, 512);
  colstats<<<240, 256, 0, stream>>>(c3p, M, 512, rpb, partials);
  bn_finalize<<<2, 256, 0, stream>>>(partials, 240, 512, M, g1b, b1b, ss3);
  colstats<<<240, 256, 0, stream>>>(scp, M, 512, rpb, partials);
  bn_finalize<<<2, 256, 0, stream>>>(partials, 240, 512, M, gc, bc, sssc);

  // out = relu(bn(c3_pre) + bn(sc_pre)), transposed to [512][M]
  final_out<<<dim3(MT, 8), 256, 0, stream>>>(c3p, scp, ss3, sssc, out, M);
}